// Round 10
// baseline (593.349 us; speedup 1.0000x reference)
//
#include <hip/hip_runtime.h>
#include <math.h>

typedef __attribute__((ext_vector_type(8))) short short8;
typedef __attribute__((ext_vector_type(4))) float floatx4;
typedef __attribute__((ext_vector_type(2))) unsigned int uintx2;

__device__ __forceinline__ float b2f(ushort u) {
    union { uint i; float f; } c; c.i = ((uint)u) << 16; return c.f;
}
__device__ __forceinline__ ushort f2b(float f) {
    union { float f; uint i; } c; c.f = f;
    return (ushort)((c.i + 0x7fffu + ((c.i >> 16) & 1u)) >> 16);
}

__device__ __forceinline__ void async_cp16(const ushort* g, ushort* l) {
    __builtin_amdgcn_global_load_lds(
        (const __attribute__((address_space(1))) void*)g,
        (__attribute__((address_space(3))) void*)l, 16, 0, 0);
}

__device__ __forceinline__ uint lds_u32(const void* p) {
    return (uint)(uintptr_t)(const __attribute__((address_space(3))) void*)p;
}

// max-reduce over the 16-lane DPP row using full-rate VALU DPP ops
__device__ __forceinline__ float dpp_max16(float x) {
    int y;
    y = __builtin_amdgcn_update_dpp(__float_as_int(x), __float_as_int(x), 0xB1, 0xF, 0xF, false);
    x = fmaxf(x, __int_as_float(y));
    y = __builtin_amdgcn_update_dpp(__float_as_int(x), __float_as_int(x), 0x4E, 0xF, 0xF, false);
    x = fmaxf(x, __int_as_float(y));
    y = __builtin_amdgcn_update_dpp(__float_as_int(x), __float_as_int(x), 0x141, 0xF, 0xF, false);
    x = fmaxf(x, __int_as_float(y));
    y = __builtin_amdgcn_update_dpp(__float_as_int(x), __float_as_int(x), 0x140, 0xF, 0xF, false);
    x = fmaxf(x, __int_as_float(y));
    return x;
}

// ---------------- fp32 [K,N] -> bf16 transposed [N,K] ----------------
__global__ __launch_bounds__(256) void cvt_t_kernel(
    const float* __restrict__ S, ushort* __restrict__ D, int K, int N)
{
    __shared__ float ls[32][33];
    const int k0 = blockIdx.y * 32, n0 = blockIdx.x * 32;
    const int t = threadIdx.x;
    const int kr = t >> 3, nc = (t & 7) * 4;
    float4 f = *(const float4*)(S + (size_t)(k0 + kr) * N + n0 + nc);
    ls[kr][nc] = f.x; ls[kr][nc + 1] = f.y; ls[kr][nc + 2] = f.z; ls[kr][nc + 3] = f.w;
    __syncthreads();
    const int nr = t >> 3, kc = (t & 7) * 4;
    ushort4 o;
    o.x = f2b(ls[kc][nr]); o.y = f2b(ls[kc + 1][nr]);
    o.z = f2b(ls[kc + 2][nr]); o.w = f2b(ls[kc + 3][nr]);
    *(ushort4*)(D + (size_t)(n0 + nr) * K + k0 + kc) = o;
}

// ---------------- LayerNorm: fp32 in, bf16 out ----------------
__global__ __launch_bounds__(256) void ln_kernel(
    const float* __restrict__ X, const float* __restrict__ G,
    const float* __restrict__ Bb, ushort* __restrict__ Y)
{
    const int row = blockIdx.x;
    const int t = threadIdx.x;
    const float* xr = X + (size_t)row * 1024;
    float4 p = ((const float4*)xr)[t];
    float s = p.x + p.y + p.z + p.w;
    float s2 = p.x * p.x + p.y * p.y + p.z * p.z + p.w * p.w;
    #pragma unroll
    for (int off = 32; off > 0; off >>= 1) {
        s += __shfl_down(s, off);
        s2 += __shfl_down(s2, off);
    }
    __shared__ float rs1[4], rs2[4];
    if ((t & 63) == 0) { rs1[t >> 6] = s; rs2[t >> 6] = s2; }
    __syncthreads();
    float S1 = rs1[0] + rs1[1] + rs1[2] + rs1[3];
    float S2 = rs2[0] + rs2[1] + rs2[2] + rs2[3];
    float mu = S1 * (1.0f / 1024.0f);
    float var = S2 * (1.0f / 1024.0f) - mu * mu;
    float rstd = rsqrtf(var + 1e-12f);
    float4 gp = ((const float4*)G)[t];
    float4 bp = ((const float4*)Bb)[t];
    ushort4 o;
    o.x = f2b((p.x - mu) * rstd * gp.x + bp.x);
    o.y = f2b((p.y - mu) * rstd * gp.y + bp.y);
    o.z = f2b((p.z - mu) * rstd * gp.z + bp.z);
    o.w = f2b((p.w - mu) * rstd * gp.w + bp.w);
    ((ushort4*)(Y + (size_t)row * 1024))[t] = o;
}

// ---------------- 256xBN 8-phase GEMM (T2+T3+T4+T5): C = A @ Bt^T ----------
// 512 threads (8 waves, 2M x 4N), BK=64. BN=256: LDS 128KB, 1 block/CU.
// Swizzle: rows are 64B = 4 chunks; involution chunk ^= (row>>1)&3 walks all
// 8 bank-slots over 16 frag rows (free 2-way). Pre-swizzled GLOBAL source.
// Schedule per K-tile kt (4 phases, counted-vmcnt ledger per r4/r6).
template<int BN, bool BIAS, bool SILU>
__global__ __launch_bounds__(512, 2) void gemm256_kernel(
    const ushort* __restrict__ A, const ushort* __restrict__ Bt,
    const float* __restrict__ bias, ushort* __restrict__ Cm,
    int M, int N, int K)
{
    constexpr int NB = BN / 64;     // B frags per wave (4 or 2)
    constexpr int BL = BN / 128;    // loads per B half-stage (2 or 1)
    __shared__ __align__(16) ushort ldsA[2][2][256][32];
    __shared__ __align__(16) ushort ldsB[2][2][BN][32];

    const int t = threadIdx.x;
    const int L = blockIdx.x + (int)(gridDim.x * blockIdx.y);
    const int cpx = (int)(gridDim.x * gridDim.y) >> 3;
    const int wg = (L & 7) * cpx + (L >> 3);
    const int m0 = (wg / gridDim.x) * 256;
    const int n0 = (wg % gridDim.x) * BN;
    const int w = t >> 6, lane = t & 63;
    const int wr = w >> 2, wc = w & 3;
    const int quad = lane >> 4, l16 = lane & 15;

    const int srow = lane >> 2;
    const int schunk = ((lane & 3) ^ ((srow >> 1) & 3)) * 8;
    const ushort* gA = A + (size_t)(m0 + w * 16 + srow) * K + schunk;
    const ushort* gB = Bt + (size_t)(n0 + w * 16 + srow) * K + schunk;
    const int NT = K >> 6;

    const int pch = (quad ^ ((l16 >> 1) & 3)) * 8;

    floatx4 acc[8][NB];
    #pragma unroll
    for (int i = 0; i < 8; ++i)
        #pragma unroll
        for (int j = 0; j < NB; ++j)
            acc[i][j] = (floatx4){0.f, 0.f, 0.f, 0.f};

    auto STAGEA = [&](int bb, int ks, int kt) {
        const ushort* g = gA + (size_t)kt * 64 + ks * 32;
        ushort* l0 = &ldsA[bb][ks][w * 16][0];
        async_cp16(g, l0);
        async_cp16(g + (size_t)128 * K, l0 + 128 * 32);
    };
    auto STAGEB = [&](int bb, int ks, int kt) {
        const ushort* g = gB + (size_t)kt * 64 + ks * 32;
        ushort* l0 = &ldsB[bb][ks][w * 16][0];
        async_cp16(g, l0);
        if constexpr (BL == 2) async_cp16(g + (size_t)128 * K, l0 + 128 * 32);
    };

    STAGEA(0, 0, 0); STAGEB(0, 0, 0);
    STAGEA(0, 1, 0); STAGEB(0, 1, 0);
    STAGEA(1, 0, 1); STAGEB(1, 0, 1);

    #pragma unroll 1
    for (int kt = 0; kt < NT; ++kt) {
        const int bb = kt & 1;
        short8 bf[NB];

        // ---- p0 ----
        if (kt < NT - 1) {
            if constexpr (BN == 256) asm volatile("s_waitcnt vmcnt(8)" ::: "memory");
            else                     asm volatile("s_waitcnt vmcnt(6)" ::: "memory");
        } else {
            if constexpr (BN == 256) asm volatile("s_waitcnt vmcnt(4)" ::: "memory");
            else                     asm volatile("s_waitcnt vmcnt(3)" ::: "memory");
        }
        __builtin_amdgcn_s_barrier();
        __builtin_amdgcn_sched_barrier(0);
        if (kt + 1 < NT) STAGEA(bb ^ 1, 1, kt + 1);
        #pragma unroll
        for (int nj = 0; nj < NB; ++nj)
            bf[nj] = *(const short8*)&ldsB[bb][0][wc * (BN / 4) + nj * 16 + l16][pch];
        {
            short8 af[4];
            #pragma unroll
            for (int mi = 0; mi < 4; ++mi)
                af[mi] = *(const short8*)&ldsA[bb][0][wr * 128 + mi * 16 + l16][pch];
            __builtin_amdgcn_s_setprio(1);
            #pragma unroll
            for (int mi = 0; mi < 4; ++mi)
                #pragma unroll
                for (int nj = 0; nj < NB; ++nj)
                    acc[mi][nj] = __builtin_amdgcn_mfma_f32_16x16x32_bf16(
                        af[mi], bf[nj], acc[mi][nj], 0, 0, 0);
            __builtin_amdgcn_s_setprio(0);
        }

        // ---- p1 ----
        if (kt + 1 < NT) STAGEB(bb ^ 1, 1, kt + 1);
        {
            short8 af[4];
            #pragma unroll
            for (int mi = 0; mi < 4; ++mi)
                af[mi] = *(const short8*)&ldsA[bb][0][wr * 128 + 64 + mi * 16 + l16][pch];
            __builtin_amdgcn_s_setprio(1);
            #pragma unroll
            for (int mi = 0; mi < 4; ++mi)
                #pragma unroll
                for (int nj = 0; nj < NB; ++nj)
                    acc[4 + mi][nj] = __builtin_amdgcn_mfma_f32_16x16x32_bf16(
                        af[mi], bf[nj], acc[4 + mi][nj], 0, 0, 0);
            __builtin_amdgcn_s_setprio(0);
        }

        // ---- p2 ----
        if (kt < NT - 1) {
            if constexpr (BN == 256) asm volatile("s_waitcnt vmcnt(8)" ::: "memory");
            else                     asm volatile("s_waitcnt vmcnt(6)" ::: "memory");
        } else {
            asm volatile("s_waitcnt vmcnt(0)" ::: "memory");
        }
        __builtin_amdgcn_s_barrier();
        __builtin_amdgcn_sched_barrier(0);
        if (kt + 2 < NT) STAGEA(bb, 0, kt + 2);
        #pragma unroll
        for (int nj = 0; nj < NB; ++nj)
            bf[nj] = *(const short8*)&ldsB[bb][1][wc * (BN / 4) + nj * 16 + l16][pch];
        {
            short8 af[4];
            #pragma unroll
            for (int mi = 0; mi < 4; ++mi)
                af[mi] = *(const short8*)&ldsA[bb][1][wr * 128 + mi * 16 + l16][pch];
            __builtin_amdgcn_s_setprio(1);
            #pragma unroll
            for (int mi = 0; mi < 4; ++mi)
                #pragma unroll
                for (int nj = 0; nj < NB; ++nj)
                    acc[mi][nj] = __builtin_amdgcn_mfma_f32_16x16x32_bf16(
                        af[mi], bf[nj], acc[mi][nj], 0, 0, 0);
            __builtin_amdgcn_s_setprio(0);
        }

        // ---- p3 ----
        if (kt + 2 < NT) STAGEB(bb, 0, kt + 2);
        {
            short8 af[4];
            #pragma unroll
            for (int mi = 0; mi < 4; ++mi)
                af[mi] = *(const short8*)&ldsA[bb][1][wr * 128 + 64 + mi * 16 + l16][pch];
            __builtin_amdgcn_s_setprio(1);
            #pragma unroll
            for (int mi = 0; mi < 4; ++mi)
                #pragma unroll
                for (int nj = 0; nj < NB; ++nj)
                    acc[4 + mi][nj] = __builtin_amdgcn_mfma_f32_16x16x32_bf16(
                        af[mi], bf[nj], acc[4 + mi][nj], 0, 0, 0);
            __builtin_amdgcn_s_setprio(0);
        }
    }

    // ---- epilogue ----
    #pragma unroll
    for (int nj = 0; nj < NB; ++nj) {
        const int n = n0 + wc * (BN / 4) + nj * 16 + l16;
        const float bv = BIAS ? bias[n] : 0.0f;
        #pragma unroll
        for (int mi = 0; mi < 8; ++mi) {
            const int mb = m0 + wr * 128 + mi * 16 + quad * 4;
            #pragma unroll
            for (int rr = 0; rr < 4; ++rr) {
                float v = acc[mi][nj][rr] + bv;
                if (SILU) v = v / (1.0f + __expf(-v));
                Cm[(size_t)(mb + rr) * N + n] = f2b(v);
            }
        }
    }
}

// ---------------- GEMM (B^T form, 128-tile): C[M,N] = A[M,K] @ Bt[N,K]^T
// r10: Wo and FFN2 moved from BN=64 to BN=128 (64-wide tiles run ~343-500 TF
// vs ~900 for 128-wide at the same structure — m92 ladder). Grids stay
// fill-exact: Wo 8x64=512 blocks, FFN2 8x32=256 blocks.
template<int BN, bool BIAS, bool SILU, bool RESID, bool OUTF32>
__global__ __launch_bounds__(256) void gemm_bt_kernel(
    const ushort* __restrict__ A, const ushort* __restrict__ Bt,
    const float* __restrict__ bias, const float* __restrict__ resid,
    void* __restrict__ Cm, int M, int N, int K)
{
    constexpr int NF = BN / 32;
    constexpr int BI = BN / 64;
    __shared__ __align__(16) ushort lsA[128 * 64];
    __shared__ __align__(16) ushort lsB[BN * 64];

    const int t = threadIdx.x;
    const int L = blockIdx.x + gridDim.x * blockIdx.y;
    const int cpx = (gridDim.x * gridDim.y) >> 3;
    const int wg = (L & 7) * cpx + (L >> 3);
    const int m0 = (wg / gridDim.x) * 128;
    const int n0 = (wg % gridDim.x) * BN;
    const int w = t >> 6;
    const int lane = t & 63;
    const int wm = (w >> 1) * 64;
    const int wn = (w & 1) * (BN / 2);
    const int quad = lane >> 4;
    const int l16 = lane & 15;

    const int lrow = lane >> 3;
    const int scol = ((lane & 7) ^ lrow) * 8;
    const ushort* gA = A + (size_t)(m0 + w * 32 + lrow) * K + scol;
    const ushort* gB = Bt + (size_t)(n0 + ((BI == 2) ? w * 32 : w * 16) + lrow) * K + scol;
    const int sw = l16 & 7;

    floatx4 acc[4][NF];
    #pragma unroll
    for (int i = 0; i < 4; ++i)
        #pragma unroll
        for (int j = 0; j < NF; ++j)
            acc[i][j] = (floatx4){0.f, 0.f, 0.f, 0.f};

    for (int k0 = 0; k0 < K; k0 += 64) {
        __syncthreads();
        #pragma unroll
        for (int i = 0; i < 4; ++i)
            async_cp16(gA + k0 + (size_t)(8 * i) * K, &lsA[(w * 32 + 8 * i) * 64]);
        if constexpr (BI == 2) {
            #pragma unroll
            for (int i = 0; i < 4; ++i)
                async_cp16(gB + k0 + (size_t)(8 * i) * K, &lsB[(w * 32 + 8 * i) * 64]);
        } else {
            #pragma unroll
            for (int i = 0; i < 2; ++i)
                async_cp16(gB + k0 + (size_t)(8 * i) * K, &lsB[(w * 16 + 8 * i) * 64]);
        }
        __syncthreads();

        #pragma unroll
        for (int h = 0; h < 2; ++h) {
            const int co = (((h << 2) | quad) ^ sw) * 8;
            short8 af[4], bf[NF];
            #pragma unroll
            for (int i = 0; i < 4; ++i)
                af[i] = *(const short8*)&lsA[(wm + i * 16 + l16) * 64 + co];
            #pragma unroll
            for (int j = 0; j < NF; ++j)
                bf[j] = *(const short8*)&lsB[(wn + j * 16 + l16) * 64 + co];
            #pragma unroll
            for (int i = 0; i < 4; ++i)
                #pragma unroll
                for (int j = 0; j < NF; ++j)
                    acc[i][j] = __builtin_amdgcn_mfma_f32_16x16x32_bf16(
                        af[i], bf[j], acc[i][j], 0, 0, 0);
        }
    }

    #pragma unroll
    for (int tn = 0; tn < NF; ++tn) {
        const int n = n0 + wn + tn * 16 + l16;
        const float bv = BIAS ? bias[n] : 0.0f;
        #pragma unroll
        for (int tm = 0; tm < 4; ++tm) {
            const int mbase = m0 + wm + tm * 16 + quad * 4;
            #pragma unroll
            for (int rr = 0; rr < 4; ++rr) {
                float v = acc[tm][tn][rr] + bv;
                if (SILU) v = v / (1.0f + __expf(-v));
                const size_t off = (size_t)(mbase + rr) * N + n;
                if (RESID) v += resid[off];
                if constexpr (OUTF32) ((float*)Cm)[off] = v;
                else                  ((ushort*)Cm)[off] = f2b(v);
            }
        }
    }
}

// ---------------- MFMA flash attention, paired q-tiles, 64 queries each ----
// (r9 attn unchanged — best measured 94.5 µs; acts as control for this round)
__global__ __launch_bounds__(256, 4) void attn_kernel(
    const ushort* __restrict__ Qm, const ushort* __restrict__ Km,
    const ushort* __restrict__ Vm, const int* __restrict__ amask,
    ushort* __restrict__ Om, int rs)
{
    __shared__ __align__(16) ushort lsQP[64][72];   // Q staging, then PT strips
    __shared__ __align__(16) ushort lsK[64][72];
    __shared__ __align__(16) ushort lsV2[2][4096];  // subtiled V, double-buffered

    const int L = blockIdx.x + (int)(gridDim.x * blockIdx.y);
    const int bh = L & 63;
    const int pr = L >> 6;                 // 0..15
    const int b = bh >> 4, h = bh & 15;
    const int t = threadIdx.x;
    const int w = t >> 6, lane = t & 63;
    const int quad = lane >> 4, l16 = lane & 15;

    const size_t base = ((size_t)b * 2048) * rs + (size_t)h * 64;
    const size_t obase = ((size_t)b * 2048) * 1024 + (size_t)h * 64;

    const int krow = t >> 3, kc8 = (t & 7) << 3;   // K staging coords
    const float scale2 = 0.125f * 1.44269504f;     // softmax in exp2 domain

    const int vkofs = ((lane >> 5) << 2) + ((lane >> 1) & 3);
    const int vdofs = ((lane >> 3) & 3) * 16 + (lane & 1) * 8;

    ushort* strip = &lsQP[w * 16][0];
    const uint strip_a = lds_u32(strip);
    char* wp_base = (char*)strip + l16 * 32 + quad * 8;   // PT write addr
    const uint rp = strip_a + quad * 256 + l16 * 8;       // PT tr-read addr

    short8 ones8;
    #pragma unroll
    for (int i = 0; i < 8; ++i) ones8[i] = (short)0x3F80;  // bf16 1.0

    #pragma unroll 1
    for (int half = 0; half < 2; ++half) {
        const int qt = half ? pr : (31 - pr);
        const int q0 = qt * 64;

        __syncthreads();   // prior half's LDS reads complete

        async_cp16(Vm + base + (size_t)(16 * w + vkofs) * rs + vdofs,
                   &lsV2[0][(4 * w) * 256]);
        async_cp16(Vm + base + (size_t)(16 * w + 8 + vkofs) * rs + vdofs,
                   &lsV2[0][(4 * w + 2) * 256]);

        #pragma unroll
        for (int it = 0; it < 2; ++it) {
            int idx = it * 256 + t;
            int row = idx >> 3, c8 = (idx & 7) << 3;
            *(int4*)&lsQP[row][c8] =
                *(const int4*)(Qm + base + (size_t)(q0 + row) * rs + c8);
        }
        __syncthreads();

        short8 aq0 = *(const short8*)&lsQP[w * 16 + l16][quad * 8];
        short8 aq1 = *(const short8*)&lsQP[w * 16 + l16][32 + quad * 8];

        floatx4 Oacc[4];
        #pragma unroll
        for (int d = 0; d < 4; ++d) Oacc[d] = (floatx4){0.f, 0.f, 0.f, 0.f};
        floatx4 Lacc = (floatx4){0.f, 0.f, 0.f, 0.f};
        float m_i[4] = {-INFINITY, -INFINITY, -INFINITY, -INFINITY};

        int4 kr0 = *(const int4*)(Km + base + (size_t)krow * rs + kc8);
        int4 kr1 = *(const int4*)(Km + base + (size_t)(32 + krow) * rs + kc8);
        int mr = amask[b * 2048 + (t & 63)];

        for (int kt = 0; kt <= qt; ++kt) {
            __syncthreads();
            *(int4*)&lsK[krow][kc8] = kr0;
            *(int4*)&lsK[32 + krow][kc8] = kr1;
            __syncthreads();

            const int mcur = mr;                    // this tile's mask (regs)
            const bool allm = __all(mcur == 1);     // wave-uniform fast path

            if (kt < qt) {
                const int kn = (kt + 1) * 64;
                kr0 = *(const int4*)(Km + base + (size_t)(kn + krow) * rs + kc8);
                kr1 = *(const int4*)(Km + base + (size_t)(kn + 32 + krow) * rs + kc8);
                mr = amask[b * 2048 + kn + (t & 63)];
                ushort* vd = &lsV2[(kt + 1) & 1][0];
                async_cp16(Vm + base + (size_t)(kn + 16 * w + vkofs) * rs + vdofs,
                           vd + (4 * w) * 256);
                async_cp16(Vm + base + (size_t)(kn + 16 * w + 8 + vkofs) * rs + vdofs,
                           vd + (4 * w + 2) * 256);
            }

            // ---- QK^T ----
            floatx4 sa[4];
            #pragma unroll
            for (int j = 0; j < 4; ++j) {
                short8 bk0 = *(const short8*)&lsK[j * 16 + l16][quad * 8];
                short8 bk1 = *(const short8*)&lsK[j * 16 + l16][32 + quad * 8];
                floatx4 z = (floatx4){0.f, 0.f, 0.f, 0.f};
                z = __builtin_amdgcn_mfma_f32_16x16x32_bf16(aq0, bk0, z, 0, 0, 0);
                sa[j] = __builtin_amdgcn_mfma_f32_16x16x32_bf16(aq1, bk1, z, 0, 0, 0);
            }

            float kb[4];
            if (!allm) {
                #pragma unroll
                for (int j = 0; j < 4; ++j)
                    kb[j] = (__shfl(mcur, j * 16 + l16) == 1) ? 0.f : -INFINITY;
            } else {
                kb[0] = kb[1] = kb[2] = kb[3] = 0.f;
            }
            const bool diag = (kt == qt);

            // ---- online softmax: lazy row-max ----
            float sv[4][4];
            float mxl[4];
            #pragma unroll
            for (int rr = 0; rr < 4; ++rr) {
                const int qrow = w * 16 + quad * 4 + rr;
                float mxv = -INFINITY;
                #pragma unroll
                for (int j = 0; j < 4; ++j) {
                    float v = sa[j][rr] * scale2 + kb[j];
                    if (diag) v = (j * 16 + l16 <= qrow) ? v : -INFINITY;
                    sv[rr][j] = v;
                    mxv = fmaxf(mxv, v);
                }
                mxl[rr] = mxv;
            }
            int grow = (mxl[0] > m_i[0] + 8.0f) | (mxl[1] > m_i[1] + 8.0f) |
                       (mxl[2] > m_i[2] + 8.0f) | (mxl[3] > m_i[3] + 8.0f);
            if (__any(grow)) {
                #pragma unroll
                for (int rr = 0; rr < 4; ++rr) {
                    const float mx = dpp_max16(mxl[rr]);
                    const float m_new = fmaxf(m_i[rr], mx);
                    const float al = exp2f(m_i[rr] - m_new);
                    m_i[rr] = m_new;
                    #pragma unroll
                    for (int d = 0; d < 4; ++d) Oacc[d][rr] *= al;
                    Lacc[rr] *= al;
                }
            }

            // ---- P -> PT strip [64 k][16 q] ----
            #pragma unroll
            for (int j = 0; j < 4; ++j) {
                float p0 = exp2f(sv[0][j] - m_i[0]);
                float p1 = exp2f(sv[1][j] - m_i[1]);
                float p2 = exp2f(sv[2][j] - m_i[2]);
                float p3 = exp2f(sv[3][j] - m_i[3]);
                uint w0, w1;
                asm("v_cvt_pk_bf16_f32 %0, %1, %2" : "=v"(w0) : "v"(p0), "v"(p1));
                asm("v_cvt_pk_bf16_f32 %0, %1, %2" : "=v"(w1) : "v"(p2), "v"(p3));
                *(uint2*)(wp_base + j * 512) = make_uint2(w0, w1);
            }

            // ---- PT -> A-frags via hardware transpose reads ----
            asm volatile("s_waitcnt lgkmcnt(0)" ::: "memory");
            uintx2 t0, t1, t2, t3;
            asm volatile("ds_read_b64_tr_b16 %0, %1 offset:0"    : "=v"(t0) : "v"(rp));
            asm volatile("ds_read_b64_tr_b16 %0, %1 offset:128"  : "=v"(t1) : "v"(rp));
            asm volatile("ds_read_b64_tr_b16 %0, %1 offset:1024" : "=v"(t2) : "v"(rp));
            asm volatile("ds_read_b64_tr_b16 %0, %1 offset:1152" : "=v"(t3) : "v"(rp));
            asm volatile("s_waitcnt lgkmcnt(0)" ::: "memory");
            __builtin_amdgcn_sched_barrier(0);
            union { short8 s; uint u[4]; } ua0, ua1;
            ua0.u[0] = t0.x; ua0.u[1] = t0.y; ua0.u[2] = t1.x; ua0.u[3] = t1.y;
            ua1.u[0] = t2.x; ua1.u[1] = t2.y; ua1.u[2] = t3.x; ua1.u[3] = t3.y;
            const short8 ap0 = ua0.s;
            const short8 ap1 = ua1.s;

            // ---- PV + L ----
            const uint vb = lds_u32(&lsV2[kt & 1][0]) + quad * 1024 + l16 * 8;
            #pragma unroll
            for (int db = 0; db < 4; ++db) {
                const uint vbd = vb + db * 128;
                uintx2 v0, v1, v2, v3;
                asm volatile("ds_read_b64_tr_b16 %0, %1 offset:0"    : "=v"(v0) : "v"(vbd));
                asm volatile("ds_read_b64_tr_b16 %0, %1 offset:512"  : "=v"(v1) : "v"(vbd));
                asm volatile("ds_read_b64_tr_b16 %0, %1 offset:4096" : "=v"(v2) : "v"(vbd));
                asm volatile("ds_read_b64_tr_b16 %0, %1 offset:4608" : "=v"(v3) : "v"(vbd));
                asm volatile("s_waitcnt lgkmcnt(0)" ::: "memory");
                __builtin_amdgcn_sched_barrier(0);
                union { short8 s; uint u[4]; } ub0, ub1;
                ub0.u[0] = v0.x; ub0.u[1] = v0.y; ub0.u[2] = v1.x; ub0.u[3] = v1.y;
                ub1.u[0] = v2.x; ub1.u[1] = v2.y; ub1.u[2] = v3.x; ub1.u[3] = v3.y;
                Oacc[db] = __builtin_amdgcn_mfma_f32_16x16x32_bf16(ap0, ub0.s, Oacc[db], 0, 0, 0);
                Oacc[db] = __builtin_amdgcn_mfma_f32_16x16x32_bf16(ap1, ub1.s, Oacc[db], 0, 0, 0);
            }
            Lacc = __builtin_amdgcn_mfma_f32_16x16x32_bf16(ap0, ones8, Lacc, 0, 0, 0);
            Lacc = __builtin_amdgcn_mfma_f32_16x16x32_bf16(ap1, ones8, Lacc, 0, 0, 0);
        }

        #pragma unroll
        for (int rr = 0; rr < 4; ++rr) {
            const float inv = 1.0f / Lacc[rr];
            const int row = q0 + w * 16 + quad * 4 + rr;
            ushort* op = Om + obase + (size_t)row * 1024;
            #pragma unroll
            for (int d = 0; d < 4; ++d)
                op[d * 16 + l16] = f2b(Oacc[d][rr] * inv);
        }
    }
}

// ---------------- driver ----------------
// ws peak 72 MiB:
//   phase 1: xa [0,16) | qkvb [16,64) | Wqkv_t [64,70) | Wo_t [70,72)
//   phase 2: W1_t [0,8) W2_t [8,16) | yb [16,32) | hb chunk [32,64)
extern "C" void kernel_launch(void* const* d_in, const int* in_sizes, int n_in,
                              void* d_out, int out_size, void* d_ws, size_t ws_size,
                              hipStream_t stream) {
    const float* hidden = (const float*)d_in[0];
    const int*   amask  = (const int*)d_in[1];
    const float* Wq  = (const float*)d_in[2];
    const float* Wk  = (const float*)d_in[3];
    const float* Wv  = (const float*)d_in[4];
    const float* Wo  = (const float*)d_in[5];
    const float* l1g = (const float*)d_in[6];
    const float* l1b = (const float*)d_in[7];
    const float* W1  = (const float*)d_in[8];
    const float* b1  = (const float*)d_in[9];
    const float* W2  = (const float*)d_in[10];
    const float* b2  = (const float*)d_in[11];
    const float* l2g = (const float*)d_in[12];
    const float* l2b = (const float*)d_in[13];

    const int M = 8192;
    const size_t MB = 1048576;
    char* ws = (char*)d_ws;
    ushort* xa    = (ushort*)(ws);
    ushort* qkvb  = (ushort*)(ws + 16 * MB);
    ushort* Wqkvt = (ushort*)(ws + 64 * MB);
    ushort* Wot   = (ushort*)(ws + 70 * MB);
    ushort* W1t   = (ushort*)(ws);
    ushort* W2t   = (ushort*)(ws + 8 * MB);
    ushort* yb    = (ushort*)(ws + 16 * MB);
    ushort* hbc   = (ushort*)(ws + 32 * MB);
    float*  x2    = (float*)d_out;

    cvt_t_kernel<<<dim3(32, 32), 256, 0, stream>>>(Wq, Wqkvt, 1024, 1024);
    cvt_t_kernel<<<dim3(32, 32), 256, 0, stream>>>(Wk, Wqkvt + (size_t)1024 * 1024, 1024, 1024);
    cvt_t_kernel<<<dim3(32, 32), 256, 0, stream>>>(Wv, Wqkvt + (size_t)2048 * 1024, 1024, 1024);
    cvt_t_kernel<<<dim3(32, 32), 256, 0, stream>>>(Wo, Wot, 1024, 1024);

    ln_kernel<<<M, 256, 0, stream>>>(hidden, l1g, l1b, xa);
    gemm256_kernel<256, false, false><<<dim3(12, 32), 512, 0, stream>>>(
        xa, Wqkvt, nullptr, qkvb, M, 3072, 1024);
    attn_kernel<<<dim3(16, 64), 256, 0, stream>>>(
        qkvb, qkvb + 1024, qkvb + 2048, amask, xa, 3072);
    gemm_bt_kernel<128, false, false, true, true><<<dim3(8, 64), 256, 0, stream>>>(
        xa, Wot, nullptr, hidden, x2, M, 1024, 1024);

    cvt_t_kernel<<<dim3(128, 32), 256, 0, stream>>>(W1, W1t, 1024, 4096);
    cvt_t_kernel<<<dim3(32, 128), 256, 0, stream>>>(W2, W2t, 4096, 1024);

    ln_kernel<<<M, 256, 0, stream>>>(x2, l2g, l2b, yb);
    for (int mc = 0; mc < 2; ++mc) {
        const size_t off = (size_t)mc * 4096 * 1024;
        gemm256_kernel<256, true, true><<<dim3(16, 16), 512, 0, stream>>>(
            yb + off, W1t, b1, hbc, 4096, 4096, 1024);
        gemm_bt_kernel<128, true, false, true, true><<<dim3(8, 32), 256, 0, stream>>>(
            hbc, W2t, b2, x2 + off, (void*)(x2 + off), 4096, 1024, 4096);
    }
}

// Round 11
// 565.525 us; speedup vs baseline: 1.0492x; 1.0492x over previous
//
#include <hip/hip_runtime.h>
#include <math.h>

typedef __attribute__((ext_vector_type(8))) short short8;
typedef __attribute__((ext_vector_type(4))) float floatx4;
typedef __attribute__((ext_vector_type(2))) unsigned int uintx2;

__device__ __forceinline__ float b2f(ushort u) {
    union { uint i; float f; } c; c.i = ((uint)u) << 16; return c.f;
}
__device__ __forceinline__ ushort f2b(float f) {
    union { float f; uint i; } c; c.f = f;
    return (ushort)((c.i + 0x7fffu + ((c.i >> 16) & 1u)) >> 16);
}

__device__ __forceinline__ void async_cp16(const ushort* g, ushort* l) {
    __builtin_amdgcn_global_load_lds(
        (const __attribute__((address_space(1))) void*)g,
        (__attribute__((address_space(3))) void*)l, 16, 0, 0);
}

__device__ __forceinline__ uint lds_u32(const void* p) {
    return (uint)(uintptr_t)(const __attribute__((address_space(3))) void*)p;
}

// max-reduce over the 16-lane DPP row using full-rate VALU DPP ops
__device__ __forceinline__ float dpp_max16(float x) {
    int y;
    y = __builtin_amdgcn_update_dpp(__float_as_int(x), __float_as_int(x), 0xB1, 0xF, 0xF, false);
    x = fmaxf(x, __int_as_float(y));
    y = __builtin_amdgcn_update_dpp(__float_as_int(x), __float_as_int(x), 0x4E, 0xF, 0xF, false);
    x = fmaxf(x, __int_as_float(y));
    y = __builtin_amdgcn_update_dpp(__float_as_int(x), __float_as_int(x), 0x141, 0xF, 0xF, false);
    x = fmaxf(x, __int_as_float(y));
    y = __builtin_amdgcn_update_dpp(__float_as_int(x), __float_as_int(x), 0x140, 0xF, 0xF, false);
    x = fmaxf(x, __int_as_float(y));
    return x;
}

// ---------------- fp32 [K,N] -> bf16 transposed [N,K] ----------------
__global__ __launch_bounds__(256) void cvt_t_kernel(
    const float* __restrict__ S, ushort* __restrict__ D, int K, int N)
{
    __shared__ float ls[32][33];
    const int k0 = blockIdx.y * 32, n0 = blockIdx.x * 32;
    const int t = threadIdx.x;
    const int kr = t >> 3, nc = (t & 7) * 4;
    float4 f = *(const float4*)(S + (size_t)(k0 + kr) * N + n0 + nc);
    ls[kr][nc] = f.x; ls[kr][nc + 1] = f.y; ls[kr][nc + 2] = f.z; ls[kr][nc + 3] = f.w;
    __syncthreads();
    const int nr = t >> 3, kc = (t & 7) * 4;
    ushort4 o;
    o.x = f2b(ls[kc][nr]); o.y = f2b(ls[kc + 1][nr]);
    o.z = f2b(ls[kc + 2][nr]); o.w = f2b(ls[kc + 3][nr]);
    *(ushort4*)(D + (size_t)(n0 + nr) * K + k0 + kc) = o;
}

// ---------------- LayerNorm: fp32 in, bf16 out ----------------
__global__ __launch_bounds__(256) void ln_kernel(
    const float* __restrict__ X, const float* __restrict__ G,
    const float* __restrict__ Bb, ushort* __restrict__ Y)
{
    const int row = blockIdx.x;
    const int t = threadIdx.x;
    const float* xr = X + (size_t)row * 1024;
    float4 p = ((const float4*)xr)[t];
    float s = p.x + p.y + p.z + p.w;
    float s2 = p.x * p.x + p.y * p.y + p.z * p.z + p.w * p.w;
    #pragma unroll
    for (int off = 32; off > 0; off >>= 1) {
        s += __shfl_down(s, off);
        s2 += __shfl_down(s2, off);
    }
    __shared__ float rs1[4], rs2[4];
    if ((t & 63) == 0) { rs1[t >> 6] = s; rs2[t >> 6] = s2; }
    __syncthreads();
    float S1 = rs1[0] + rs1[1] + rs1[2] + rs1[3];
    float S2 = rs2[0] + rs2[1] + rs2[2] + rs2[3];
    float mu = S1 * (1.0f / 1024.0f);
    float var = S2 * (1.0f / 1024.0f) - mu * mu;
    float rstd = rsqrtf(var + 1e-12f);
    float4 gp = ((const float4*)G)[t];
    float4 bp = ((const float4*)Bb)[t];
    ushort4 o;
    o.x = f2b((p.x - mu) * rstd * gp.x + bp.x);
    o.y = f2b((p.y - mu) * rstd * gp.y + bp.y);
    o.z = f2b((p.z - mu) * rstd * gp.z + bp.z);
    o.w = f2b((p.w - mu) * rstd * gp.w + bp.w);
    ((ushort4*)(Y + (size_t)row * 1024))[t] = o;
}

// ---------------- 256xBN 8-phase GEMM (T2+T3+T4+T5): C = A @ Bt^T ----------
// 512 threads (8 waves, 2M x 4N), BK=64. BN=256: LDS 128KB, 1 block/CU.
// Swizzle: rows are 64B = 4 chunks; involution chunk ^= (row>>1)&3 walks all
// 8 bank-slots over 16 frag rows (free 2-way). Pre-swizzled GLOBAL source.
// Schedule per K-tile kt (4 phases, counted-vmcnt ledger per r4/r6).
template<int BN, bool BIAS, bool SILU>
__global__ __launch_bounds__(512, 2) void gemm256_kernel(
    const ushort* __restrict__ A, const ushort* __restrict__ Bt,
    const float* __restrict__ bias, ushort* __restrict__ Cm,
    int M, int N, int K)
{
    constexpr int NB = BN / 64;     // B frags per wave (4 or 2)
    constexpr int BL = BN / 128;    // loads per B half-stage (2 or 1)
    __shared__ __align__(16) ushort ldsA[2][2][256][32];
    __shared__ __align__(16) ushort ldsB[2][2][BN][32];

    const int t = threadIdx.x;
    const int L = blockIdx.x + (int)(gridDim.x * blockIdx.y);
    const int cpx = (int)(gridDim.x * gridDim.y) >> 3;
    const int wg = (L & 7) * cpx + (L >> 3);
    const int m0 = (wg / gridDim.x) * 256;
    const int n0 = (wg % gridDim.x) * BN;
    const int w = t >> 6, lane = t & 63;
    const int wr = w >> 2, wc = w & 3;
    const int quad = lane >> 4, l16 = lane & 15;

    const int srow = lane >> 2;
    const int schunk = ((lane & 3) ^ ((srow >> 1) & 3)) * 8;
    const ushort* gA = A + (size_t)(m0 + w * 16 + srow) * K + schunk;
    const ushort* gB = Bt + (size_t)(n0 + w * 16 + srow) * K + schunk;
    const int NT = K >> 6;

    const int pch = (quad ^ ((l16 >> 1) & 3)) * 8;

    floatx4 acc[8][NB];
    #pragma unroll
    for (int i = 0; i < 8; ++i)
        #pragma unroll
        for (int j = 0; j < NB; ++j)
            acc[i][j] = (floatx4){0.f, 0.f, 0.f, 0.f};

    auto STAGEA = [&](int bb, int ks, int kt) {
        const ushort* g = gA + (size_t)kt * 64 + ks * 32;
        ushort* l0 = &ldsA[bb][ks][w * 16][0];
        async_cp16(g, l0);
        async_cp16(g + (size_t)128 * K, l0 + 128 * 32);
    };
    auto STAGEB = [&](int bb, int ks, int kt) {
        const ushort* g = gB + (size_t)kt * 64 + ks * 32;
        ushort* l0 = &ldsB[bb][ks][w * 16][0];
        async_cp16(g, l0);
        if constexpr (BL == 2) async_cp16(g + (size_t)128 * K, l0 + 128 * 32);
    };

    STAGEA(0, 0, 0); STAGEB(0, 0, 0);
    STAGEA(0, 1, 0); STAGEB(0, 1, 0);
    STAGEA(1, 0, 1); STAGEB(1, 0, 1);

    #pragma unroll 1
    for (int kt = 0; kt < NT; ++kt) {
        const int bb = kt & 1;
        short8 bf[NB];

        // ---- p0 ----
        if (kt < NT - 1) {
            if constexpr (BN == 256) asm volatile("s_waitcnt vmcnt(8)" ::: "memory");
            else                     asm volatile("s_waitcnt vmcnt(6)" ::: "memory");
        } else {
            if constexpr (BN == 256) asm volatile("s_waitcnt vmcnt(4)" ::: "memory");
            else                     asm volatile("s_waitcnt vmcnt(3)" ::: "memory");
        }
        __builtin_amdgcn_s_barrier();
        __builtin_amdgcn_sched_barrier(0);
        if (kt + 1 < NT) STAGEA(bb ^ 1, 1, kt + 1);
        #pragma unroll
        for (int nj = 0; nj < NB; ++nj)
            bf[nj] = *(const short8*)&ldsB[bb][0][wc * (BN / 4) + nj * 16 + l16][pch];
        {
            short8 af[4];
            #pragma unroll
            for (int mi = 0; mi < 4; ++mi)
                af[mi] = *(const short8*)&ldsA[bb][0][wr * 128 + mi * 16 + l16][pch];
            __builtin_amdgcn_s_setprio(1);
            #pragma unroll
            for (int mi = 0; mi < 4; ++mi)
                #pragma unroll
                for (int nj = 0; nj < NB; ++nj)
                    acc[mi][nj] = __builtin_amdgcn_mfma_f32_16x16x32_bf16(
                        af[mi], bf[nj], acc[mi][nj], 0, 0, 0);
            __builtin_amdgcn_s_setprio(0);
        }

        // ---- p1 ----
        if (kt + 1 < NT) STAGEB(bb ^ 1, 1, kt + 1);
        {
            short8 af[4];
            #pragma unroll
            for (int mi = 0; mi < 4; ++mi)
                af[mi] = *(const short8*)&ldsA[bb][0][wr * 128 + 64 + mi * 16 + l16][pch];
            __builtin_amdgcn_s_setprio(1);
            #pragma unroll
            for (int mi = 0; mi < 4; ++mi)
                #pragma unroll
                for (int nj = 0; nj < NB; ++nj)
                    acc[4 + mi][nj] = __builtin_amdgcn_mfma_f32_16x16x32_bf16(
                        af[mi], bf[nj], acc[4 + mi][nj], 0, 0, 0);
            __builtin_amdgcn_s_setprio(0);
        }

        // ---- p2 ----
        if (kt < NT - 1) {
            if constexpr (BN == 256) asm volatile("s_waitcnt vmcnt(8)" ::: "memory");
            else                     asm volatile("s_waitcnt vmcnt(6)" ::: "memory");
        } else {
            asm volatile("s_waitcnt vmcnt(0)" ::: "memory");
        }
        __builtin_amdgcn_s_barrier();
        __builtin_amdgcn_sched_barrier(0);
        if (kt + 2 < NT) STAGEA(bb, 0, kt + 2);
        #pragma unroll
        for (int nj = 0; nj < NB; ++nj)
            bf[nj] = *(const short8*)&ldsB[bb][1][wc * (BN / 4) + nj * 16 + l16][pch];
        {
            short8 af[4];
            #pragma unroll
            for (int mi = 0; mi < 4; ++mi)
                af[mi] = *(const short8*)&ldsA[bb][1][wr * 128 + mi * 16 + l16][pch];
            __builtin_amdgcn_s_setprio(1);
            #pragma unroll
            for (int mi = 0; mi < 4; ++mi)
                #pragma unroll
                for (int nj = 0; nj < NB; ++nj)
                    acc[mi][nj] = __builtin_amdgcn_mfma_f32_16x16x32_bf16(
                        af[mi], bf[nj], acc[mi][nj], 0, 0, 0);
            __builtin_amdgcn_s_setprio(0);
        }

        // ---- p3 ----
        if (kt + 2 < NT) STAGEB(bb, 0, kt + 2);
        {
            short8 af[4];
            #pragma unroll
            for (int mi = 0; mi < 4; ++mi)
                af[mi] = *(const short8*)&ldsA[bb][1][wr * 128 + 64 + mi * 16 + l16][pch];
            __builtin_amdgcn_s_setprio(1);
            #pragma unroll
            for (int mi = 0; mi < 4; ++mi)
                #pragma unroll
                for (int nj = 0; nj < NB; ++nj)
                    acc[4 + mi][nj] = __builtin_amdgcn_mfma_f32_16x16x32_bf16(
                        af[mi], bf[nj], acc[4 + mi][nj], 0, 0, 0);
            __builtin_amdgcn_s_setprio(0);
        }
    }

    // ---- epilogue ----
    #pragma unroll
    for (int nj = 0; nj < NB; ++nj) {
        const int n = n0 + wc * (BN / 4) + nj * 16 + l16;
        const float bv = BIAS ? bias[n] : 0.0f;
        #pragma unroll
        for (int mi = 0; mi < 8; ++mi) {
            const int mb = m0 + wr * 128 + mi * 16 + quad * 4;
            #pragma unroll
            for (int rr = 0; rr < 4; ++rr) {
                float v = acc[mi][nj][rr] + bv;
                if (SILU) v = v / (1.0f + __expf(-v));
                Cm[(size_t)(mb + rr) * N + n] = f2b(v);
            }
        }
    }
}

// ---------------- GEMM (B^T form, 128-tile): C[M,N] = A[M,K] @ Bt[N,K]^T
// r11: Wo/FFN2 back on BN=64 (r10's BN=128 regressed −25 µs: it cut FFN2 to
// 1 block/CU and Wo to 2/CU — cross-block overlap, not tile width, is what
// hides this structure's barrier-drain stall. blocks/CU >= 2 wins here.)
template<int BN, bool BIAS, bool SILU, bool RESID, bool OUTF32>
__global__ __launch_bounds__(256) void gemm_bt_kernel(
    const ushort* __restrict__ A, const ushort* __restrict__ Bt,
    const float* __restrict__ bias, const float* __restrict__ resid,
    void* __restrict__ Cm, int M, int N, int K)
{
    constexpr int NF = BN / 32;
    constexpr int BI = BN / 64;
    __shared__ __align__(16) ushort lsA[128 * 64];
    __shared__ __align__(16) ushort lsB[BN * 64];

    const int t = threadIdx.x;
    const int L = blockIdx.x + gridDim.x * blockIdx.y;
    const int cpx = (gridDim.x * gridDim.y) >> 3;
    const int wg = (L & 7) * cpx + (L >> 3);
    const int m0 = (wg / gridDim.x) * 128;
    const int n0 = (wg % gridDim.x) * BN;
    const int w = t >> 6;
    const int lane = t & 63;
    const int wm = (w >> 1) * 64;
    const int wn = (w & 1) * (BN / 2);
    const int quad = lane >> 4;
    const int l16 = lane & 15;

    const int lrow = lane >> 3;
    const int scol = ((lane & 7) ^ lrow) * 8;
    const ushort* gA = A + (size_t)(m0 + w * 32 + lrow) * K + scol;
    const ushort* gB = Bt + (size_t)(n0 + ((BI == 2) ? w * 32 : w * 16) + lrow) * K + scol;
    const int sw = l16 & 7;

    floatx4 acc[4][NF];
    #pragma unroll
    for (int i = 0; i < 4; ++i)
        #pragma unroll
        for (int j = 0; j < NF; ++j)
            acc[i][j] = (floatx4){0.f, 0.f, 0.f, 0.f};

    for (int k0 = 0; k0 < K; k0 += 64) {
        __syncthreads();
        #pragma unroll
        for (int i = 0; i < 4; ++i)
            async_cp16(gA + k0 + (size_t)(8 * i) * K, &lsA[(w * 32 + 8 * i) * 64]);
        if constexpr (BI == 2) {
            #pragma unroll
            for (int i = 0; i < 4; ++i)
                async_cp16(gB + k0 + (size_t)(8 * i) * K, &lsB[(w * 32 + 8 * i) * 64]);
        } else {
            #pragma unroll
            for (int i = 0; i < 2; ++i)
                async_cp16(gB + k0 + (size_t)(8 * i) * K, &lsB[(w * 16 + 8 * i) * 64]);
        }
        __syncthreads();

        #pragma unroll
        for (int h = 0; h < 2; ++h) {
            const int co = (((h << 2) | quad) ^ sw) * 8;
            short8 af[4], bf[NF];
            #pragma unroll
            for (int i = 0; i < 4; ++i)
                af[i] = *(const short8*)&lsA[(wm + i * 16 + l16) * 64 + co];
            #pragma unroll
            for (int j = 0; j < NF; ++j)
                bf[j] = *(const short8*)&lsB[(wn + j * 16 + l16) * 64 + co];
            #pragma unroll
            for (int i = 0; i < 4; ++i)
                #pragma unroll
                for (int j = 0; j < NF; ++j)
                    acc[i][j] = __builtin_amdgcn_mfma_f32_16x16x32_bf16(
                        af[i], bf[j], acc[i][j], 0, 0, 0);
        }
    }

    #pragma unroll
    for (int tn = 0; tn < NF; ++tn) {
        const int n = n0 + wn + tn * 16 + l16;
        const float bv = BIAS ? bias[n] : 0.0f;
        #pragma unroll
        for (int tm = 0; tm < 4; ++tm) {
            const int mbase = m0 + wm + tm * 16 + quad * 4;
            #pragma unroll
            for (int rr = 0; rr < 4; ++rr) {
                float v = acc[tm][tn][rr] + bv;
                if (SILU) v = v / (1.0f + __expf(-v));
                const size_t off = (size_t)(mbase + rr) * N + n;
                if (RESID) v += resid[off];
                if constexpr (OUTF32) ((float*)Cm)[off] = v;
                else                  ((ushort*)Cm)[off] = f2b(v);
            }
        }
    }
}

// ---------------- MFMA flash attention, paired q-tiles, 64 queries each ----
// r11 = r9 attn + T5 s_setprio(1) around the QK^T and PV MFMA clusters.
// Regime: 4 independent blocks/CU at different pipeline phases (the m191
// attn regime where setprio measured +4-7%), unlike lockstep GEMM (m190 null).
__global__ __launch_bounds__(256, 4) void attn_kernel(
    const ushort* __restrict__ Qm, const ushort* __restrict__ Km,
    const ushort* __restrict__ Vm, const int* __restrict__ amask,
    ushort* __restrict__ Om, int rs)
{
    __shared__ __align__(16) ushort lsQP[64][72];   // Q staging, then PT strips
    __shared__ __align__(16) ushort lsK[64][72];
    __shared__ __align__(16) ushort lsV2[2][4096];  // subtiled V, double-buffered

    const int L = blockIdx.x + (int)(gridDim.x * blockIdx.y);
    const int bh = L & 63;
    const int pr = L >> 6;                 // 0..15
    const int b = bh >> 4, h = bh & 15;
    const int t = threadIdx.x;
    const int w = t >> 6, lane = t & 63;
    const int quad = lane >> 4, l16 = lane & 15;

    const size_t base = ((size_t)b * 2048) * rs + (size_t)h * 64;
    const size_t obase = ((size_t)b * 2048) * 1024 + (size_t)h * 64;

    const int krow = t >> 3, kc8 = (t & 7) << 3;   // K staging coords
    const float scale2 = 0.125f * 1.44269504f;     // softmax in exp2 domain

    const int vkofs = ((lane >> 5) << 2) + ((lane >> 1) & 3);
    const int vdofs = ((lane >> 3) & 3) * 16 + (lane & 1) * 8;

    ushort* strip = &lsQP[w * 16][0];
    const uint strip_a = lds_u32(strip);
    char* wp_base = (char*)strip + l16 * 32 + quad * 8;   // PT write addr
    const uint rp = strip_a + quad * 256 + l16 * 8;       // PT tr-read addr

    short8 ones8;
    #pragma unroll
    for (int i = 0; i < 8; ++i) ones8[i] = (short)0x3F80;  // bf16 1.0

    #pragma unroll 1
    for (int half = 0; half < 2; ++half) {
        const int qt = half ? pr : (31 - pr);
        const int q0 = qt * 64;

        __syncthreads();   // prior half's LDS reads complete

        async_cp16(Vm + base + (size_t)(16 * w + vkofs) * rs + vdofs,
                   &lsV2[0][(4 * w) * 256]);
        async_cp16(Vm + base + (size_t)(16 * w + 8 + vkofs) * rs + vdofs,
                   &lsV2[0][(4 * w + 2) * 256]);

        #pragma unroll
        for (int it = 0; it < 2; ++it) {
            int idx = it * 256 + t;
            int row = idx >> 3, c8 = (idx & 7) << 3;
            *(int4*)&lsQP[row][c8] =
                *(const int4*)(Qm + base + (size_t)(q0 + row) * rs + c8);
        }
        __syncthreads();

        short8 aq0 = *(const short8*)&lsQP[w * 16 + l16][quad * 8];
        short8 aq1 = *(const short8*)&lsQP[w * 16 + l16][32 + quad * 8];

        floatx4 Oacc[4];
        #pragma unroll
        for (int d = 0; d < 4; ++d) Oacc[d] = (floatx4){0.f, 0.f, 0.f, 0.f};
        floatx4 Lacc = (floatx4){0.f, 0.f, 0.f, 0.f};
        float m_i[4] = {-INFINITY, -INFINITY, -INFINITY, -INFINITY};

        int4 kr0 = *(const int4*)(Km + base + (size_t)krow * rs + kc8);
        int4 kr1 = *(const int4*)(Km + base + (size_t)(32 + krow) * rs + kc8);
        int mr = amask[b * 2048 + (t & 63)];

        for (int kt = 0; kt <= qt; ++kt) {
            __syncthreads();
            *(int4*)&lsK[krow][kc8] = kr0;
            *(int4*)&lsK[32 + krow][kc8] = kr1;
            __syncthreads();

            const int mcur = mr;                    // this tile's mask (regs)
            const bool allm = __all(mcur == 1);     // wave-uniform fast path

            if (kt < qt) {
                const int kn = (kt + 1) * 64;
                kr0 = *(const int4*)(Km + base + (size_t)(kn + krow) * rs + kc8);
                kr1 = *(const int4*)(Km + base + (size_t)(kn + 32 + krow) * rs + kc8);
                mr = amask[b * 2048 + kn + (t & 63)];
                ushort* vd = &lsV2[(kt + 1) & 1][0];
                async_cp16(Vm + base + (size_t)(kn + 16 * w + vkofs) * rs + vdofs,
                           vd + (4 * w) * 256);
                async_cp16(Vm + base + (size_t)(kn + 16 * w + 8 + vkofs) * rs + vdofs,
                           vd + (4 * w + 2) * 256);
            }

            // ---- QK^T ----
            floatx4 sa[4];
            __builtin_amdgcn_s_setprio(1);
            #pragma unroll
            for (int j = 0; j < 4; ++j) {
                short8 bk0 = *(const short8*)&lsK[j * 16 + l16][quad * 8];
                short8 bk1 = *(const short8*)&lsK[j * 16 + l16][32 + quad * 8];
                floatx4 z = (floatx4){0.f, 0.f, 0.f, 0.f};
                z = __builtin_amdgcn_mfma_f32_16x16x32_bf16(aq0, bk0, z, 0, 0, 0);
                sa[j] = __builtin_amdgcn_mfma_f32_16x16x32_bf16(aq1, bk1, z, 0, 0, 0);
            }
            __builtin_amdgcn_s_setprio(0);

            float kb[4];
            if (!allm) {
                #pragma unroll
                for (int j = 0; j < 4; ++j)
                    kb[j] = (__shfl(mcur, j * 16 + l16) == 1) ? 0.f : -INFINITY;
            } else {
                kb[0] = kb[1] = kb[2] = kb[3] = 0.f;
            }
            const bool diag = (kt == qt);

            // ---- online softmax: lazy row-max ----
            float sv[4][4];
            float mxl[4];
            #pragma unroll
            for (int rr = 0; rr < 4; ++rr) {
                const int qrow = w * 16 + quad * 4 + rr;
                float mxv = -INFINITY;
                #pragma unroll
                for (int j = 0; j < 4; ++j) {
                    float v = sa[j][rr] * scale2 + kb[j];
                    if (diag) v = (j * 16 + l16 <= qrow) ? v : -INFINITY;
                    sv[rr][j] = v;
                    mxv = fmaxf(mxv, v);
                }
                mxl[rr] = mxv;
            }
            int grow = (mxl[0] > m_i[0] + 8.0f) | (mxl[1] > m_i[1] + 8.0f) |
                       (mxl[2] > m_i[2] + 8.0f) | (mxl[3] > m_i[3] + 8.0f);
            if (__any(grow)) {
                #pragma unroll
                for (int rr = 0; rr < 4; ++rr) {
                    const float mx = dpp_max16(mxl[rr]);
                    const float m_new = fmaxf(m_i[rr], mx);
                    const float al = exp2f(m_i[rr] - m_new);
                    m_i[rr] = m_new;
                    #pragma unroll
                    for (int d = 0; d < 4; ++d) Oacc[d][rr] *= al;
                    Lacc[rr] *= al;
                }
            }

            // ---- P -> PT strip [64 k][16 q] ----
            #pragma unroll
            for (int j = 0; j < 4; ++j) {
                float p0 = exp2f(sv[0][j] - m_i[0]);
                float p1 = exp2f(sv[1][j] - m_i[1]);
                float p2 = exp2f(sv[2][j] - m_i[2]);
                float p3 = exp2f(sv[3][j] - m_i[3]);
                uint w0, w1;
                asm("v_cvt_pk_bf16_f32 %0, %1, %2" : "=v"(w0) : "v"(p0), "v"(p1));
                asm("v_cvt_pk_bf16_f32 %0, %1, %2" : "=v"(w1) : "v"(p2), "v"(p3));
                *(uint2*)(wp_base + j * 512) = make_uint2(w0, w1);
            }

            // ---- PT -> A-frags via hardware transpose reads ----
            asm volatile("s_waitcnt lgkmcnt(0)" ::: "memory");
            uintx2 t0, t1, t2, t3;
            asm volatile("ds_read_b64_tr_b16 %0, %1 offset:0"    : "=v"(t0) : "v"(rp));
            asm volatile("ds_read_b64_tr_b16 %0, %1 offset:128"  : "=v"(t1) : "v"(rp));
            asm volatile("ds_read_b64_tr_b16 %0, %1 offset:1024" : "=v"(t2) : "v"(rp));
            asm volatile("ds_read_b64_tr_b16 %0, %1 offset:1152" : "=v"(t3) : "v"(rp));
            asm volatile("s_waitcnt lgkmcnt(0)" ::: "memory");
            __builtin_amdgcn_sched_barrier(0);
            union { short8 s; uint u[4]; } ua0, ua1;
            ua0.u[0] = t0.x; ua0.u[1] = t0.y; ua0.u[2] = t1.x; ua0.u[3] = t1.y;
            ua1.u[0] = t2.x; ua1.u[1] = t2.y; ua1.u[2] = t3.x; ua1.u[3] = t3.y;
            const short8 ap0 = ua0.s;
            const short8 ap1 = ua1.s;

            // ---- PV + L ----
            const uint vb = lds_u32(&lsV2[kt & 1][0]) + quad * 1024 + l16 * 8;
            __builtin_amdgcn_s_setprio(1);
            #pragma unroll
            for (int db = 0; db < 4; ++db) {
                const uint vbd = vb + db * 128;
                uintx2 v0, v1, v2, v3;
                asm volatile("ds_read_b64_tr_b16 %0, %1 offset:0"    : "=v"(v0) : "v"(vbd));
                asm volatile("ds_read_b64_tr_b16 %0, %1 offset:512"  : "=v"(v1) : "v"(vbd));
                asm volatile("ds_read_b64_tr_b16 %0, %1 offset:4096" : "=v"(v2) : "v"(vbd));
                asm volatile("ds_read_b64_tr_b16 %0, %1 offset:4608" : "=v"(v3) : "v"(vbd));
                asm volatile("s_waitcnt lgkmcnt(0)" ::: "memory");
                __builtin_amdgcn_sched_barrier(0);
                union { short8 s; uint u[4]; } ub0, ub1;
                ub0.u[0] = v0.x; ub0.u[1] = v0.y; ub0.u[2] = v1.x; ub0.u[3] = v1.y;
                ub1.u[0] = v2.x; ub1.u[1] = v2.y; ub1.u[2] = v3.x; ub1.u[3] = v3.y;
                Oacc[db] = __builtin_amdgcn_mfma_f32_16x16x32_bf16(ap0, ub0.s, Oacc[db], 0, 0, 0);
                Oacc[db] = __builtin_amdgcn_mfma_f32_16x16x32_bf16(ap1, ub1.s, Oacc[db], 0, 0, 0);
            }
            Lacc = __builtin_amdgcn_mfma_f32_16x16x32_bf16(ap0, ones8, Lacc, 0, 0, 0);
            Lacc = __builtin_amdgcn_mfma_f32_16x16x32_bf16(ap1, ones8, Lacc, 0, 0, 0);
            __builtin_amdgcn_s_setprio(0);
        }

        #pragma unroll
        for (int rr = 0; rr < 4; ++rr) {
            const float inv = 1.0f / Lacc[rr];
            const int row = q0 + w * 16 + quad * 4 + rr;
            ushort* op = Om + obase + (size_t)row * 1024;
            #pragma unroll
            for (int d = 0; d < 4; ++d)
                op[d * 16 + l16] = f2b(Oacc[d][rr] * inv);
        }
    }
}

// ---------------- driver ----------------
// ws peak 72 MiB:
//   phase 1: xa [0,16) | qkvb [16,64) | Wqkv_t [64,70) | Wo_t [70,72)
//   phase 2: W1_t [0,8) W2_t [8,16) | yb [16,32) | hb chunk [32,64)
extern "C" void kernel_launch(void* const* d_in, const int* in_sizes, int n_in,
                              void* d_out, int out_size, void* d_ws, size_t ws_size,
                              hipStream_t stream) {
    const float* hidden = (const float*)d_in[0];
    const int*   amask  = (const int*)d_in[1];
    const float* Wq  = (const float*)d_in[2];
    const float* Wk  = (const float*)d_in[3];
    const float* Wv  = (const float*)d_in[4];
    const float* Wo  = (const float*)d_in[5];
    const float* l1g = (const float*)d_in[6];
    const float* l1b = (const float*)d_in[7];
    const float* W1  = (const float*)d_in[8];
    const float* b1  = (const float*)d_in[9];
    const float* W2  = (const float*)d_in[10];
    const float* b2  = (const float*)d_in[11];
    const float* l2g = (const float*)d_in[12];
    const float* l2b = (const float*)d_in[13];

    const int M = 8192;
    const size_t MB = 1048576;
    char* ws = (char*)d_ws;
    ushort* xa    = (ushort*)(ws);
    ushort* qkvb  = (ushort*)(ws + 16 * MB);
    ushort* Wqkvt = (ushort*)(ws + 64 * MB);
    ushort* Wot   = (ushort*)(ws + 70 * MB);
    ushort* W1t   = (ushort*)(ws);
    ushort* W2t   = (ushort*)(ws + 8 * MB);
    ushort* yb    = (ushort*)(ws + 16 * MB);
    ushort* hbc   = (ushort*)(ws + 32 * MB);
    float*  x2    = (float*)d_out;

    cvt_t_kernel<<<dim3(32, 32), 256, 0, stream>>>(Wq, Wqkvt, 1024, 1024);
    cvt_t_kernel<<<dim3(32, 32), 256, 0, stream>>>(Wk, Wqkvt + (size_t)1024 * 1024, 1024, 1024);
    cvt_t_kernel<<<dim3(32, 32), 256, 0, stream>>>(Wv, Wqkvt + (size_t)2048 * 1024, 1024, 1024);
    cvt_t_kernel<<<dim3(32, 32), 256, 0, stream>>>(Wo, Wot, 1024, 1024);

    ln_kernel<<<M, 256, 0, stream>>>(hidden, l1g, l1b, xa);
    gemm256_kernel<256, false, false><<<dim3(12, 32), 512, 0, stream>>>(
        xa, Wqkvt, nullptr, qkvb, M, 3072, 1024);
    attn_kernel<<<dim3(16, 64), 256, 0, stream>>>(
        qkvb, qkvb + 1024, qkvb + 2048, amask, xa, 3072);
    gemm_bt_kernel<64, false, false, true, true><<<dim3(16, 64), 256, 0, stream>>>(
        xa, Wot, nullptr, hidden, x2, M, 1024, 1024);

    cvt_t_kernel<<<dim3(128, 32), 256, 0, stream>>>(W1, W1t, 1024, 4096);
    cvt_t_kernel<<<dim3(32, 128), 256, 0, stream>>>(W2, W2t, 4096, 1024);

    ln_kernel<<<M, 256, 0, stream>>>(x2, l2g, l2b, yb);
    for (int mc = 0; mc < 2; ++mc) {
        const size_t off = (size_t)mc * 4096 * 1024;
        gemm256_kernel<256, true, true><<<dim3(16, 16), 512, 0, stream>>>(
            yb + off, W1t, b1, hbc, 4096, 4096, 1024);
        gemm_bt_kernel<64, true, false, true, true><<<dim3(16, 32), 256, 0, stream>>>(
            hbc, W2t, b2, x2 + off, (void*)(x2 + off), 4096, 1024, 4096);
    }
}